// Round 9
// baseline (574.080 us; speedup 1.0000x reference)
//
#include <hip/hip_runtime.h>
#include <math.h>

typedef unsigned short u16;
typedef unsigned int   u32;
typedef __bf16  bf16x8 __attribute__((ext_vector_type(8)));
typedef float   f32x4  __attribute__((ext_vector_type(4)));

#define B_  4
#define T_  2048
#define D_  1024
#define H_  16
#define HD_ 64
#define M_  (B_*T_)   // 8192
#define NEG_BIG (-30000.0f)

__device__ __forceinline__ float bf2f(u16 h) {
    u32 u = ((u32)h) << 16;
    return __uint_as_float(u);
}
__device__ __forceinline__ u16 f2bf(float f) {
    u32 u = __float_as_uint(f);
    u32 r = (u + 0x7fffu + ((u >> 16) & 1u)) >> 16;
    return (u16)r;
}
__device__ __forceinline__ void async_copy16(const u16* g, u16* l) {
    __builtin_amdgcn_global_load_lds(
        (const __attribute__((address_space(1))) u32*)g,
        (__attribute__((address_space(3))) u32*)l, 16, 0, 0);
}

// ---------------------------------------------------------------------------
// x (fp32) -> bf16, vectorized. 8 elements/thread.
// ---------------------------------------------------------------------------
__global__ __launch_bounds__(256)
void convert_x(const float* __restrict__ X, u16* __restrict__ Xb)
{
    const int id = (blockIdx.x * 256 + threadIdx.x) * 8;
    float4 f0 = *(const float4*)(X + id);
    float4 f1 = *(const float4*)(X + id + 4);
    union { u16 t[8]; uint4 v; } c;
    c.t[0] = f2bf(f0.x); c.t[1] = f2bf(f0.y); c.t[2] = f2bf(f0.z); c.t[3] = f2bf(f0.w);
    c.t[4] = f2bf(f1.x); c.t[5] = f2bf(f1.y); c.t[6] = f2bf(f1.z); c.t[7] = f2bf(f1.w);
    *(uint4*)(Xb + id) = c.v;
}

// ---------------------------------------------------------------------------
// bf16 MFMA GEMM, B^T layout, m97 structure (unchanged from R8).
// ---------------------------------------------------------------------------
template<int OUT_F32>
__global__ __launch_bounds__(256)
void gemm_bt(const u16* __restrict__ A, const u16* __restrict__ Bt_base,
             const float* __restrict__ bias0, const float* __restrict__ bias1,
             const float* __restrict__ bias2,
             void* __restrict__ C_base, int M, int N, int K)
{
    const int z = blockIdx.z;
    const u16* Bt  = Bt_base + (size_t)z * N * K;
    const float* bias = (z == 0) ? bias0 : ((z == 1) ? bias1 : bias2);

    const int m0 = blockIdx.x * 128, n0 = blockIdx.y * 128;
    const int tid = threadIdx.x, lane = tid & 63, wave = tid >> 6;
    const int wm = (wave >> 1) * 64, wn = (wave & 1) * 64;
    const int quad = lane >> 4, l16 = lane & 15;

    __shared__ __align__(16) u16 As[128 * 32];
    __shared__ __align__(16) u16 Bs[128 * 32];

    f32x4 acc[4][4];
#pragma unroll
    for (int i = 0; i < 4; i++)
#pragma unroll
        for (int j = 0; j < 4; j++) acc[i][j] = (f32x4){0.f, 0.f, 0.f, 0.f};

    for (int k0 = 0; k0 < K; k0 += 32) {
        __syncthreads();
#pragma unroll
        for (int i = 0; i < 2; i++) {
            int idx = i * 256 + tid;
            int r = idx >> 2, c = (idx & 3) * 8;
            async_copy16(A  + (size_t)(m0 + r) * K + k0 + c, &As[idx * 8]);
            async_copy16(Bt + (size_t)(n0 + r) * K + k0 + c, &Bs[idx * 8]);
        }
        __syncthreads();

        bf16x8 af[4], bfr[4];
#pragma unroll
        for (int mi = 0; mi < 4; mi++)
            af[mi] = *(const bf16x8*)&As[(wm + mi * 16 + l16) * 32 + quad * 8];
#pragma unroll
        for (int ni = 0; ni < 4; ni++)
            bfr[ni] = *(const bf16x8*)&Bs[(wn + ni * 16 + l16) * 32 + quad * 8];
#pragma unroll
        for (int mi = 0; mi < 4; mi++)
#pragma unroll
            for (int ni = 0; ni < 4; ni++)
                acc[mi][ni] = __builtin_amdgcn_mfma_f32_16x16x32_bf16(
                    af[mi], bfr[ni], acc[mi][ni], 0, 0, 0);
    }

    float bv[4];
#pragma unroll
    for (int ni = 0; ni < 4; ni++) bv[ni] = bias[n0 + wn + ni * 16 + l16];
#pragma unroll
    for (int mi = 0; mi < 4; mi++) {
#pragma unroll
        for (int reg = 0; reg < 4; reg++) {
            int row = m0 + wm + mi * 16 + quad * 4 + reg;
#pragma unroll
            for (int ni = 0; ni < 4; ni++) {
                int col = n0 + wn + ni * 16 + l16;
                float v = acc[mi][ni][reg] + bv[ni];
                if (OUT_F32)
                    ((float*)C_base + (size_t)z * M * N)[(size_t)row * N + col] = v;
                else
                    ((u16*)C_base + (size_t)z * M * N)[(size_t)row * N + col] = f2bf(v);
            }
        }
    }
}

// ---------------------------------------------------------------------------
// Transpose + convert fp32 weight (D x D) -> bf16 Wt[n][k] = W[k][n].
// ---------------------------------------------------------------------------
__global__ __launch_bounds__(256)
void transpose_w(const float* __restrict__ w0, const float* __restrict__ w1,
                 const float* __restrict__ w2,
                 u16* __restrict__ out)
{
    const int z = blockIdx.z;
    const float* W = (z == 0) ? w0 : ((z == 1) ? w1 : w2);
    u16* Wt = out + (size_t)z * D_ * D_;
    const int k0 = blockIdx.x * 64, n0 = blockIdx.y * 64;
    __shared__ u16 tl[64][72];
    const int tid = threadIdx.x;
    const int r = tid >> 2, c4 = (tid & 3) * 16;
#pragma unroll
    for (int j = 0; j < 4; j++) {
        float4 fv = *(const float4*)(W + (size_t)(k0 + r) * D_ + n0 + c4 + j * 4);
        tl[r][c4 + j * 4 + 0] = f2bf(fv.x);
        tl[r][c4 + j * 4 + 1] = f2bf(fv.y);
        tl[r][c4 + j * 4 + 2] = f2bf(fv.z);
        tl[r][c4 + j * 4 + 3] = f2bf(fv.w);
    }
    __syncthreads();
    u16 vals[16];
#pragma unroll
    for (int j = 0; j < 16; j++) vals[j] = tl[c4 + j][r];
#pragma unroll
    for (int j = 0; j < 2; j++)
        *(uint4*)(Wt + (size_t)(n0 + r) * D_ + k0 + c4 + j * 8) =
            *(const uint4*)&vals[j * 8];
}

// ---------------------------------------------------------------------------
// Transpose V (B,T,H,HD) bf16 -> Vt (B,H,HD,T) bf16
// ---------------------------------------------------------------------------
__global__ __launch_bounds__(256)
void transpose_v(const u16* __restrict__ V, u16* __restrict__ Vt)
{
    const int t0 = blockIdx.x * 64;
    const int h = blockIdx.y, b = blockIdx.z;
    __shared__ u16 tl[64][72];
    const int tid = threadIdx.x;
    const int r = tid >> 2, c4 = (tid & 3) * 16;
    const u16* Vg = V + ((size_t)(b * T_ + t0)) * D_ + h * HD_;
#pragma unroll
    for (int j = 0; j < 2; j++)
        *(uint4*)&tl[r][c4 + j * 8] =
            *(const uint4*)(Vg + (size_t)r * D_ + c4 + j * 8);
    __syncthreads();
    u16 vals[16];
#pragma unroll
    for (int j = 0; j < 16; j++) vals[j] = tl[c4 + j][r];
    u16* Og = Vt + ((size_t)(b * H_ + h)) * HD_ * T_ + (size_t)r * T_ + t0 + c4;
#pragma unroll
    for (int j = 0; j < 2; j++)
        *(uint4*)(Og + j * 8) = *(const uint4*)&vals[j * 8];
}

// ---------------------------------------------------------------------------
// RoPE on Q and K in place (bf16); cos/sin fp32.
// ---------------------------------------------------------------------------
__global__ __launch_bounds__(256)
void rope_qk(u16* __restrict__ Q, u16* __restrict__ K,
             const float* __restrict__ cosb, const float* __restrict__ sinb)
{
    int g  = blockIdx.x * 256 + threadIdx.x;
    int d  = g & 31;
    int h  = (g >> 5) & (H_ - 1);
    int bt = g >> 9;
    int t  = bt & (T_ - 1);
    size_t off = (size_t)bt * D_ + h * HD_ + d;
    float c1 = cosb[t * HD_ + d],      s1 = sinb[t * HD_ + d];
    float c2 = cosb[t * HD_ + d + 32], s2 = sinb[t * HD_ + d + 32];
    {
        float x1 = bf2f(Q[off]), x2 = bf2f(Q[off + 32]);
        Q[off]      = f2bf(x1 * c1 - x2 * s1);
        Q[off + 32] = f2bf(x2 * c2 + x1 * s2);
    }
    {
        float x1 = bf2f(K[off]), x2 = bf2f(K[off + 32]);
        K[off]      = f2bf(x1 * c1 - x2 * s1);
        K[off + 32] = f2bf(x2 * c2 + x1 * s2);
    }
}

// ---------------------------------------------------------------------------
// Causal MFMA flash attention, v3:
//  - Software-pipelined K/V prefetch: tile kb+1's global loads issued into
//    registers right after tile kb's LDS publish -> latency overlaps compute.
//  - 3 barriers/iter (R7 cadence restored: R8 measured barrier removal as a
//    regression).
//  - Heavy-first block order: qb = 31 - blockIdx.x (tail shrink).
// ---------------------------------------------------------------------------
__global__ __launch_bounds__(256)
void attn_kernel(const u16* __restrict__ Q, const u16* __restrict__ K,
                 const u16* __restrict__ Vt, u16* __restrict__ O)
{
    const int qb = 31 - blockIdx.x;       // heavy blocks first
    const int h = blockIdx.y, b = blockIdx.z;
    const int tid = threadIdx.x, lane = tid & 63, wave = tid >> 6;
    const int quad = lane >> 4, l16 = lane & 15;

    __shared__ __align__(16) u16 Ks[128 * 72];
    __shared__ __align__(16) u16 Vs[64 * 136];
    __shared__ __align__(16) u16 Ps[64 * 136];

    // Q fragments in registers: row = qb*64 + wave*16 + l16
    const u16* Qr = Q + ((size_t)(b * T_ + qb * 64 + wave * 16 + l16)) * D_ + h * HD_;
    bf16x8 qf[2];
    qf[0] = *(const bf16x8*)(Qr + quad * 8);
    qf[1] = *(const bf16x8*)(Qr + 32 + quad * 8);

    // staging registers + load helper
    const u16* Kbase = K + ((size_t)(b * T_)) * D_ + h * HD_;
    const u16* Vbase = Vt + ((size_t)(b * H_ + h)) * HD_ * T_;
    const int kr = (tid * 4) >> 3;            // rows for K staging (idx=i*256+tid)
    uint4 kreg[4], vreg[4];

    const int nkb = (qb >> 1) + 1;

    // prologue: prefetch tile 0
    {
        const u16* Kg = Kbase;
        const u16* Vg = Vbase;
#pragma unroll
        for (int i = 0; i < 4; i++) {
            int idx = i * 256 + tid;
            kreg[i] = *(const uint4*)(Kg + (size_t)(idx >> 3) * D_ + (idx & 7) * 8);
            vreg[i] = *(const uint4*)(Vg + (size_t)(idx >> 4) * T_ + (idx & 15) * 8);
        }
    }
    (void)kr;

    f32x4 o_acc[4];
#pragma unroll
    for (int i = 0; i < 4; i++) o_acc[i] = (f32x4){0.f, 0.f, 0.f, 0.f};
    float m_i[4], l_i[4];
#pragma unroll
    for (int r = 0; r < 4; r++) { m_i[r] = NEG_BIG; l_i[r] = 0.f; }

    for (int kb = 0; kb < nkb; kb++) {
        __syncthreads();   // all waves done reading previous tile's LDS
        // publish tile kb from registers
#pragma unroll
        for (int i = 0; i < 4; i++) {
            int idx = i * 256 + tid;
            *(uint4*)&Ks[(idx >> 3) * 72 + (idx & 7) * 8] = kreg[i];
            *(uint4*)&Vs[(idx >> 4) * 136 + (idx & 15) * 8] = vreg[i];
        }
        __syncthreads();   // tile kb visible

        // prefetch tile kb+1 (overlaps with compute below)
        if (kb + 1 < nkb) {
            const u16* Kg = Kbase + (size_t)(kb + 1) * 128 * D_;
            const u16* Vg = Vbase + (size_t)(kb + 1) * 128;
#pragma unroll
            for (int i = 0; i < 4; i++) {
                int idx = i * 256 + tid;
                kreg[i] = *(const uint4*)(Kg + (size_t)(idx >> 3) * D_ + (idx & 7) * 8);
                vreg[i] = *(const uint4*)(Vg + (size_t)(idx >> 4) * T_ + (idx & 15) * 8);
            }
        }

        // S = Q K^T
        f32x4 s[8];
#pragma unroll
        for (int ni = 0; ni < 8; ni++) s[ni] = (f32x4){0.f, 0.f, 0.f, 0.f};
#pragma unroll
        for (int ks = 0; ks < 2; ks++) {
#pragma unroll
            for (int ni = 0; ni < 8; ni++) {
                bf16x8 bb = *(const bf16x8*)&Ks[(ni * 16 + l16) * 72 + ks * 32 + quad * 8];
                s[ni] = __builtin_amdgcn_mfma_f32_16x16x32_bf16(qf[ks], bb, s[ni], 0, 0, 0);
            }
        }

        const int qrow0 = qb * 64 + wave * 16 + quad * 4;
        const int col0 = kb * 128 + l16;
        const bool maskit = (kb == nkb - 1);
        float mnew[4];
#pragma unroll
        for (int r = 0; r < 4; r++) mnew[r] = m_i[r];
        if (maskit) {
#pragma unroll
            for (int ni = 0; ni < 8; ni++)
#pragma unroll
                for (int r = 0; r < 4; r++) {
                    float v = s[ni][r] * 0.125f;
                    v = (col0 + ni * 16 <= qrow0 + r) ? v : NEG_BIG;
                    s[ni][r] = v;
                    mnew[r] = fmaxf(mnew[r], v);
                }
        } else {
#pragma unroll
            for (int ni = 0; ni < 8; ni++)
#pragma unroll
                for (int r = 0; r < 4; r++) {
                    float v = s[ni][r] * 0.125f;
                    s[ni][r] = v;
                    mnew[r] = fmaxf(mnew[r], v);
                }
        }
#pragma unroll
        for (int off = 1; off < 16; off <<= 1)
#pragma unroll
            for (int r = 0; r < 4; r++)
                mnew[r] = fmaxf(mnew[r], __shfl_xor(mnew[r], off, 64));

        float alpha[4], rs[4];
#pragma unroll
        for (int r = 0; r < 4; r++) {
            alpha[r] = __expf(m_i[r] - mnew[r]);
            rs[r] = 0.f;
            m_i[r] = mnew[r];
        }
#pragma unroll
        for (int ni = 0; ni < 8; ni++)
#pragma unroll
            for (int r = 0; r < 4; r++) {
                float p = __expf(s[ni][r] - mnew[r]);
                rs[r] += p;
                Ps[(wave * 16 + quad * 4 + r) * 136 + ni * 16 + l16] = f2bf(p);
            }
#pragma unroll
        for (int off = 1; off < 16; off <<= 1)
#pragma unroll
            for (int r = 0; r < 4; r++) rs[r] += __shfl_xor(rs[r], off, 64);
#pragma unroll
        for (int r = 0; r < 4; r++) l_i[r] = l_i[r] * alpha[r] + rs[r];
#pragma unroll
        for (int ni = 0; ni < 4; ni++)
#pragma unroll
            for (int r = 0; r < 4; r++) o_acc[ni][r] *= alpha[r];

        __syncthreads();   // R7 cadence: sync before PV (measured faster in R7)

        // O += P V
#pragma unroll
        for (int k0 = 0; k0 < 128; k0 += 32) {
            bf16x8 a = *(const bf16x8*)&Ps[(wave * 16 + l16) * 136 + k0 + quad * 8];
#pragma unroll
            for (int ni = 0; ni < 4; ni++) {
                bf16x8 bb = *(const bf16x8*)&Vs[(ni * 16 + l16) * 136 + k0 + quad * 8];
                o_acc[ni] = __builtin_amdgcn_mfma_f32_16x16x32_bf16(a, bb, o_acc[ni], 0, 0, 0);
            }
        }
    }

    float inv_l[4];
#pragma unroll
    for (int r = 0; r < 4; r++) inv_l[r] = 1.f / fmaxf(l_i[r], 1e-30f);
    u16* Og = O + ((size_t)(b * T_ + qb * 64)) * D_ + h * HD_;
#pragma unroll
    for (int ni = 0; ni < 4; ni++)
#pragma unroll
        for (int r = 0; r < 4; r++)
            Og[(size_t)(wave * 16 + quad * 4 + r) * D_ + ni * 16 + l16] =
                f2bf(o_acc[ni][r] * inv_l[r]);
}

// ---------------------------------------------------------------------------
// Workspace (u16 elements), 32M used (64 MiB):
//   ws [0,  8M): Qbuf; attn O aliases it (per-(row,col) read-then-write)
//   ws [8, 16M): Kbuf; after attn -> WtO at [8M, 9M)
//   ws [16,24M): Vbuf
//   ws [24,27M): WtQKV (dead after QKV gemm) -> Vtbuf [24M, 32M)
//   d_out:       first 16 MB = xb (bf16 x) until QKV gemm; then fp32 output
// ---------------------------------------------------------------------------
extern "C" void kernel_launch(void* const* d_in, const int* in_sizes, int n_in,
                              void* d_out, int out_size, void* d_ws, size_t ws_size,
                              hipStream_t stream)
{
    (void)in_sizes; (void)n_in; (void)out_size; (void)ws_size;
    const float* x    = (const float*)d_in[0];
    const float* cosb = (const float*)d_in[2];
    const float* sinb = (const float*)d_in[3];
    const float* Wq   = (const float*)d_in[4];
    const float* bq   = (const float*)d_in[5];
    const float* Wk   = (const float*)d_in[6];
    const float* bk   = (const float*)d_in[7];
    const float* Wv   = (const float*)d_in[8];
    const float* bv   = (const float*)d_in[9];
    const float* Wo   = (const float*)d_in[10];
    const float* bo   = (const float*)d_in[11];

    u16* ws = (u16*)d_ws;
    const size_t MD = (size_t)M_ * D_;
    u16* xb     = (u16*)d_out;
    u16* Qbuf   = ws;
    u16* Kbuf   = ws + MD;
    u16* Vbuf   = ws + 2 * MD;
    u16* WtQKV  = ws + 3 * MD;
    u16* Vtbuf  = ws + 3 * MD;
    u16* WtO    = ws + MD;
    u16* Abuf   = ws;

    convert_x<<<dim3(M_ * D_ / 2048), 256, 0, stream>>>(x, xb);
    transpose_w<<<dim3(16, 16, 3), 256, 0, stream>>>(Wq, Wk, Wv, WtQKV);
    gemm_bt<0><<<dim3(64, 8, 3), 256, 0, stream>>>(xb, WtQKV, bq, bk, bv,
                                                   Qbuf, M_, D_, D_);
    rope_qk<<<dim3((B_ * T_ * H_ * 32) / 256), 256, 0, stream>>>(
        Qbuf, Kbuf, cosb, sinb);
    transpose_v<<<dim3(32, 16, 4), 256, 0, stream>>>(Vbuf, Vtbuf);
    attn_kernel<<<dim3(32, 16, 4), 256, 0, stream>>>(Qbuf, Kbuf, Vtbuf, Abuf);
    transpose_w<<<dim3(16, 16, 1), 256, 0, stream>>>(Wo, Wo, Wo, WtO);
    gemm_bt<1><<<dim3(64, 8, 1), 256, 0, stream>>>(Abuf, WtO, bo, bo, bo,
                                                   d_out, M_, D_, D_);
}

// Round 10
// 430.460 us; speedup vs baseline: 1.3336x; 1.3336x over previous
//
#include <hip/hip_runtime.h>
#include <math.h>

typedef unsigned short u16;
typedef unsigned int   u32;
typedef __bf16  bf16x8 __attribute__((ext_vector_type(8)));
typedef float   f32x4  __attribute__((ext_vector_type(4)));

#define B_  4
#define T_  2048
#define D_  1024
#define H_  16
#define HD_ 64
#define M_  (B_*T_)   // 8192
#define NEG_BIG (-30000.0f)

__device__ __forceinline__ float bf2f(u16 h) {
    u32 u = ((u32)h) << 16;
    return __uint_as_float(u);
}
__device__ __forceinline__ u16 f2bf(float f) {
    u32 u = __float_as_uint(f);
    u32 r = (u + 0x7fffu + ((u >> 16) & 1u)) >> 16;
    return (u16)r;
}
__device__ __forceinline__ void async_copy16(const u16* g, u16* l) {
    __builtin_amdgcn_global_load_lds(
        (const __attribute__((address_space(1))) u32*)g,
        (__attribute__((address_space(3))) u32*)l, 16, 0, 0);
}

// ---------------------------------------------------------------------------
// x (fp32) -> bf16, vectorized. 8 elements/thread.
// ---------------------------------------------------------------------------
__global__ __launch_bounds__(256)
void convert_x(const float* __restrict__ X, u16* __restrict__ Xb)
{
    const int id = (blockIdx.x * 256 + threadIdx.x) * 8;
    float4 f0 = *(const float4*)(X + id);
    float4 f1 = *(const float4*)(X + id + 4);
    union { u16 t[8]; uint4 v; } c;
    c.t[0] = f2bf(f0.x); c.t[1] = f2bf(f0.y); c.t[2] = f2bf(f0.z); c.t[3] = f2bf(f0.w);
    c.t[4] = f2bf(f1.x); c.t[5] = f2bf(f1.y); c.t[6] = f2bf(f1.z); c.t[7] = f2bf(f1.w);
    *(uint4*)(Xb + id) = c.v;
}

// ---------------------------------------------------------------------------
// bf16 MFMA GEMM, B^T layout, m97 structure (unchanged from R8/R9).
// ---------------------------------------------------------------------------
template<int OUT_F32>
__global__ __launch_bounds__(256)
void gemm_bt(const u16* __restrict__ A, const u16* __restrict__ Bt_base,
             const float* __restrict__ bias0, const float* __restrict__ bias1,
             const float* __restrict__ bias2,
             void* __restrict__ C_base, int M, int N, int K)
{
    const int z = blockIdx.z;
    const u16* Bt  = Bt_base + (size_t)z * N * K;
    const float* bias = (z == 0) ? bias0 : ((z == 1) ? bias1 : bias2);

    const int m0 = blockIdx.x * 128, n0 = blockIdx.y * 128;
    const int tid = threadIdx.x, lane = tid & 63, wave = tid >> 6;
    const int wm = (wave >> 1) * 64, wn = (wave & 1) * 64;
    const int quad = lane >> 4, l16 = lane & 15;

    __shared__ __align__(16) u16 As[128 * 32];
    __shared__ __align__(16) u16 Bs[128 * 32];

    f32x4 acc[4][4];
#pragma unroll
    for (int i = 0; i < 4; i++)
#pragma unroll
        for (int j = 0; j < 4; j++) acc[i][j] = (f32x4){0.f, 0.f, 0.f, 0.f};

    for (int k0 = 0; k0 < K; k0 += 32) {
        __syncthreads();
#pragma unroll
        for (int i = 0; i < 2; i++) {
            int idx = i * 256 + tid;
            int r = idx >> 2, c = (idx & 3) * 8;
            async_copy16(A  + (size_t)(m0 + r) * K + k0 + c, &As[idx * 8]);
            async_copy16(Bt + (size_t)(n0 + r) * K + k0 + c, &Bs[idx * 8]);
        }
        __syncthreads();

        bf16x8 af[4], bfr[4];
#pragma unroll
        for (int mi = 0; mi < 4; mi++)
            af[mi] = *(const bf16x8*)&As[(wm + mi * 16 + l16) * 32 + quad * 8];
#pragma unroll
        for (int ni = 0; ni < 4; ni++)
            bfr[ni] = *(const bf16x8*)&Bs[(wn + ni * 16 + l16) * 32 + quad * 8];
#pragma unroll
        for (int mi = 0; mi < 4; mi++)
#pragma unroll
            for (int ni = 0; ni < 4; ni++)
                acc[mi][ni] = __builtin_amdgcn_mfma_f32_16x16x32_bf16(
                    af[mi], bfr[ni], acc[mi][ni], 0, 0, 0);
    }

    float bv[4];
#pragma unroll
    for (int ni = 0; ni < 4; ni++) bv[ni] = bias[n0 + wn + ni * 16 + l16];
#pragma unroll
    for (int mi = 0; mi < 4; mi++) {
#pragma unroll
        for (int reg = 0; reg < 4; reg++) {
            int row = m0 + wm + mi * 16 + quad * 4 + reg;
#pragma unroll
            for (int ni = 0; ni < 4; ni++) {
                int col = n0 + wn + ni * 16 + l16;
                float v = acc[mi][ni][reg] + bv[ni];
                if (OUT_F32)
                    ((float*)C_base + (size_t)z * M * N)[(size_t)row * N + col] = v;
                else
                    ((u16*)C_base + (size_t)z * M * N)[(size_t)row * N + col] = f2bf(v);
            }
        }
    }
}

// ---------------------------------------------------------------------------
// Transpose + convert fp32 weight (D x D) -> bf16 Wt[n][k] = W[k][n].
// ---------------------------------------------------------------------------
__global__ __launch_bounds__(256)
void transpose_w(const float* __restrict__ w0, const float* __restrict__ w1,
                 const float* __restrict__ w2,
                 u16* __restrict__ out)
{
    const int z = blockIdx.z;
    const float* W = (z == 0) ? w0 : ((z == 1) ? w1 : w2);
    u16* Wt = out + (size_t)z * D_ * D_;
    const int k0 = blockIdx.x * 64, n0 = blockIdx.y * 64;
    __shared__ u16 tl[64][72];
    const int tid = threadIdx.x;
    const int r = tid >> 2, c4 = (tid & 3) * 16;
#pragma unroll
    for (int j = 0; j < 4; j++) {
        float4 fv = *(const float4*)(W + (size_t)(k0 + r) * D_ + n0 + c4 + j * 4);
        tl[r][c4 + j * 4 + 0] = f2bf(fv.x);
        tl[r][c4 + j * 4 + 1] = f2bf(fv.y);
        tl[r][c4 + j * 4 + 2] = f2bf(fv.z);
        tl[r][c4 + j * 4 + 3] = f2bf(fv.w);
    }
    __syncthreads();
    u16 vals[16];
#pragma unroll
    for (int j = 0; j < 16; j++) vals[j] = tl[c4 + j][r];
#pragma unroll
    for (int j = 0; j < 2; j++)
        *(uint4*)(Wt + (size_t)(n0 + r) * D_ + k0 + c4 + j * 8) =
            *(const uint4*)&vals[j * 8];
}

// ---------------------------------------------------------------------------
// Transpose V (B,T,H,HD) bf16 -> Vt (B,H,HD,T) bf16
// ---------------------------------------------------------------------------
__global__ __launch_bounds__(256)
void transpose_v(const u16* __restrict__ V, u16* __restrict__ Vt)
{
    const int t0 = blockIdx.x * 64;
    const int h = blockIdx.y, b = blockIdx.z;
    __shared__ u16 tl[64][72];
    const int tid = threadIdx.x;
    const int r = tid >> 2, c4 = (tid & 3) * 16;
    const u16* Vg = V + ((size_t)(b * T_ + t0)) * D_ + h * HD_;
#pragma unroll
    for (int j = 0; j < 2; j++)
        *(uint4*)&tl[r][c4 + j * 8] =
            *(const uint4*)(Vg + (size_t)r * D_ + c4 + j * 8);
    __syncthreads();
    u16 vals[16];
#pragma unroll
    for (int j = 0; j < 16; j++) vals[j] = tl[c4 + j][r];
    u16* Og = Vt + ((size_t)(b * H_ + h)) * HD_ * T_ + (size_t)r * T_ + t0 + c4;
#pragma unroll
    for (int j = 0; j < 2; j++)
        *(uint4*)(Og + j * 8) = *(const uint4*)&vals[j * 8];
}

// ---------------------------------------------------------------------------
// RoPE on Q and K in place (bf16); cos/sin fp32.
// ---------------------------------------------------------------------------
__global__ __launch_bounds__(256)
void rope_qk(u16* __restrict__ Q, u16* __restrict__ K,
             const float* __restrict__ cosb, const float* __restrict__ sinb)
{
    int g  = blockIdx.x * 256 + threadIdx.x;
    int d  = g & 31;
    int h  = (g >> 5) & (H_ - 1);
    int bt = g >> 9;
    int t  = bt & (T_ - 1);
    size_t off = (size_t)bt * D_ + h * HD_ + d;
    float c1 = cosb[t * HD_ + d],      s1 = sinb[t * HD_ + d];
    float c2 = cosb[t * HD_ + d + 32], s2 = sinb[t * HD_ + d + 32];
    {
        float x1 = bf2f(Q[off]), x2 = bf2f(Q[off + 32]);
        Q[off]      = f2bf(x1 * c1 - x2 * s1);
        Q[off + 32] = f2bf(x2 * c2 + x1 * s2);
    }
    {
        float x1 = bf2f(K[off]), x2 = bf2f(K[off + 32]);
        K[off]      = f2bf(x1 * c1 - x2 * s1);
        K[off + 32] = f2bf(x2 * c2 + x1 * s2);
    }
}

// ---------------------------------------------------------------------------
// Causal MFMA flash attention, v4:
//  - K/V staged via global_load_lds (no VGPR round trip; drained at barrier)
//  - Slab LDS layouts [slab][rows][32]: async-legal AND 2-way-free bank access
//  - Row-sum l_i via ones-column MFMA (no rs shuffle reduction)
//  - Q fragments pre-scaled by 1/8 (exact in bf16); no per-element scale
//  - R7 3-barrier cadence (measured best); mask only on diagonal tile
// ---------------------------------------------------------------------------
__global__ __launch_bounds__(256)
void attn_kernel(const u16* __restrict__ Q, const u16* __restrict__ K,
                 const u16* __restrict__ Vt, u16* __restrict__ O)
{
    const int qb = 31 - blockIdx.x;       // heavy blocks first
    const int h = blockIdx.y, b = blockIdx.z;
    const int tid = threadIdx.x, lane = tid & 63, wave = tid >> 6;
    const int quad = lane >> 4, l16 = lane & 15;

    __shared__ __align__(16) u16 Ks[2 * 128 * 32];   // [ks][row][32]
    __shared__ __align__(16) u16 Vs[4 * 64 * 32];    // [kslab][vrow][32]
    __shared__ __align__(16) u16 Ps[64 * 132];       // stride 132: conflict-free

    // Q fragments in registers, pre-scaled by 0.125 (exact exponent shift)
    const u16* Qr = Q + ((size_t)(b * T_ + qb * 64 + wave * 16 + l16)) * D_ + h * HD_;
    bf16x8 qf[2];
    {
        union { u16 t[8]; bf16x8 v; } a, c;
#pragma unroll
        for (int ks = 0; ks < 2; ks++) {
            a.v = *(const bf16x8*)(Qr + ks * 32 + quad * 8);
#pragma unroll
            for (int j = 0; j < 8; j++) c.t[j] = f2bf(bf2f(a.t[j]) * 0.125f);
            qf[ks] = c.v;
        }
    }

    // ones-column B fragment: B[k][0]=1, other cols 0
    bf16x8 ones_frag;
    {
        union { u16 t[8]; bf16x8 v; } o;
        const u16 one = (l16 == 0) ? (u16)0x3F80 : (u16)0;
#pragma unroll
        for (int j = 0; j < 8; j++) o.t[j] = one;
        ones_frag = o.v;
    }

    const u16* Kbase = K + ((size_t)(b * T_)) * D_ + h * HD_;
    const u16* Vbase = Vt + ((size_t)(b * H_ + h)) * HD_ * T_;

    f32x4 o_acc[4], o_l;
#pragma unroll
    for (int i = 0; i < 4; i++) o_acc[i] = (f32x4){0.f, 0.f, 0.f, 0.f};
    o_l = (f32x4){0.f, 0.f, 0.f, 0.f};
    float m_i[4];
#pragma unroll
    for (int r = 0; r < 4; r++) m_i[r] = NEG_BIG;

    const int nkb = (qb >> 1) + 1;
    for (int kb = 0; kb < nkb; kb++) {
        __syncthreads();   // all waves done reading previous tile's LDS
        {
            const u16* Kg = Kbase + (size_t)kb * 128 * D_;
            const u16* Vg = Vbase + (size_t)kb * 128;
#pragma unroll
            for (int i = 0; i < 4; i++) {
                int idx = i * 256 + tid;
                // K: slab=idx>>9 (k-half), row=(idx>>2)&127, h4=idx&3
                async_copy16(Kg + (size_t)((idx >> 2) & 127) * D_
                                + (idx >> 9) * 32 + (idx & 3) * 8,
                             &Ks[idx * 8]);
                // V: slab=idx>>8 (k-quarter), vrow=(idx>>2)&63, h4=idx&3
                async_copy16(Vg + (size_t)((idx >> 2) & 63) * T_
                                + (idx >> 8) * 32 + (idx & 3) * 8,
                             &Vs[idx * 8]);
            }
        }
        __syncthreads();   // vmcnt drained -> tile kb visible

        // S = (Q/8) K^T
        f32x4 s[8];
#pragma unroll
        for (int ni = 0; ni < 8; ni++) s[ni] = (f32x4){0.f, 0.f, 0.f, 0.f};
#pragma unroll
        for (int ks = 0; ks < 2; ks++) {
#pragma unroll
            for (int ni = 0; ni < 8; ni++) {
                bf16x8 bb = *(const bf16x8*)&Ks[ks * 4096 + (ni * 16 + l16) * 32 + quad * 8];
                s[ni] = __builtin_amdgcn_mfma_f32_16x16x32_bf16(qf[ks], bb, s[ni], 0, 0, 0);
            }
        }

        const int qrow0 = qb * 64 + wave * 16 + quad * 4;
        const int col0 = kb * 128 + l16;
        float mnew[4];
#pragma unroll
        for (int r = 0; r < 4; r++) mnew[r] = m_i[r];
        if (kb == nkb - 1) {
#pragma unroll
            for (int ni = 0; ni < 8; ni++)
#pragma unroll
                for (int r = 0; r < 4; r++) {
                    float v = (col0 + ni * 16 <= qrow0 + r) ? s[ni][r] : NEG_BIG;
                    s[ni][r] = v;
                    mnew[r] = fmaxf(mnew[r], v);
                }
        } else {
#pragma unroll
            for (int ni = 0; ni < 8; ni++)
#pragma unroll
                for (int r = 0; r < 4; r++)
                    mnew[r] = fmaxf(mnew[r], s[ni][r]);
        }
#pragma unroll
        for (int off = 1; off < 16; off <<= 1)
#pragma unroll
            for (int r = 0; r < 4; r++)
                mnew[r] = fmaxf(mnew[r], __shfl_xor(mnew[r], off, 64));

        float alpha[4];
#pragma unroll
        for (int r = 0; r < 4; r++) {
            alpha[r] = __expf(m_i[r] - mnew[r]);
            m_i[r] = mnew[r];
        }
#pragma unroll
        for (int ni = 0; ni < 8; ni++)
#pragma unroll
            for (int r = 0; r < 4; r++) {
                float p = __expf(s[ni][r] - mnew[r]);
                Ps[(wave * 16 + quad * 4 + r) * 132 + ni * 16 + l16] = f2bf(p);
            }
#pragma unroll
        for (int ni = 0; ni < 4; ni++)
#pragma unroll
            for (int r = 0; r < 4; r++) o_acc[ni][r] *= alpha[r];
#pragma unroll
        for (int r = 0; r < 4; r++) o_l[r] *= alpha[r];

        __syncthreads();   // R7 cadence (measured best)

        // O += P V ; l += P * ones
#pragma unroll
        for (int k0 = 0; k0 < 128; k0 += 32) {
            bf16x8 a = *(const bf16x8*)&Ps[(wave * 16 + l16) * 132 + k0 + quad * 8];
#pragma unroll
            for (int ni = 0; ni < 4; ni++) {
                bf16x8 bb = *(const bf16x8*)&Vs[(k0 >> 5) * 2048 + (ni * 16 + l16) * 32 + quad * 8];
                o_acc[ni] = __builtin_amdgcn_mfma_f32_16x16x32_bf16(a, bb, o_acc[ni], 0, 0, 0);
            }
            o_l = __builtin_amdgcn_mfma_f32_16x16x32_bf16(a, ones_frag, o_l, 0, 0, 0);
        }
    }

    // l_i lives in col 0 (lane l16==0) of o_l; broadcast within 16-lane group
    float inv_l[4];
#pragma unroll
    for (int r = 0; r < 4; r++) {
        float lv = __shfl(o_l[r], lane & 48, 64);
        inv_l[r] = 1.f / fmaxf(lv, 1e-30f);
    }
    u16* Og = O + ((size_t)(b * T_ + qb * 64)) * D_ + h * HD_;
#pragma unroll
    for (int ni = 0; ni < 4; ni++)
#pragma unroll
        for (int r = 0; r < 4; r++)
            Og[(size_t)(wave * 16 + quad * 4 + r) * D_ + ni * 16 + l16] =
                f2bf(o_acc[ni][r] * inv_l[r]);
}

// ---------------------------------------------------------------------------
// Workspace (u16 elements), 32M used (64 MiB):
//   ws [0,  8M): Qbuf; attn O aliases it (per-(row,col) read-then-write)
//   ws [8, 16M): Kbuf; after attn -> WtO at [8M, 9M)
//   ws [16,24M): Vbuf
//   ws [24,27M): WtQKV (dead after QKV gemm) -> Vtbuf [24M, 32M)
//   d_out:       first 16 MB = xb (bf16 x) until QKV gemm; then fp32 output
// ---------------------------------------------------------------------------
extern "C" void kernel_launch(void* const* d_in, const int* in_sizes, int n_in,
                              void* d_out, int out_size, void* d_ws, size_t ws_size,
                              hipStream_t stream)
{
    (void)in_sizes; (void)n_in; (void)out_size; (void)ws_size;
    const float* x    = (const float*)d_in[0];
    const float* cosb = (const float*)d_in[2];
    const float* sinb = (const float*)d_in[3];
    const float* Wq   = (const float*)d_in[4];
    const float* bq   = (const float*)d_in[5];
    const float* Wk   = (const float*)d_in[6];
    const float* bk   = (const float*)d_in[7];
    const float* Wv   = (const float*)d_in[8];
    const float* bv   = (const float*)d_in[9];
    const float* Wo   = (const float*)d_in[10];
    const float* bo   = (const float*)d_in[11];

    u16* ws = (u16*)d_ws;
    const size_t MD = (size_t)M_ * D_;
    u16* xb     = (u16*)d_out;
    u16* Qbuf   = ws;
    u16* Kbuf   = ws + MD;
    u16* Vbuf   = ws + 2 * MD;
    u16* WtQKV  = ws + 3 * MD;
    u16* Vtbuf  = ws + 3 * MD;
    u16* WtO    = ws + MD;
    u16* Abuf   = ws;

    convert_x<<<dim3(M_ * D_ / 2048), 256, 0, stream>>>(x, xb);
    transpose_w<<<dim3(16, 16, 3), 256, 0, stream>>>(Wq, Wk, Wv, WtQKV);
    gemm_bt<0><<<dim3(64, 8, 3), 256, 0, stream>>>(xb, WtQKV, bq, bk, bv,
                                                   Qbuf, M_, D_, D_);
    rope_qk<<<dim3((B_ * T_ * H_ * 32) / 256), 256, 0, stream>>>(
        Qbuf, Kbuf, cosb, sinb);
    transpose_v<<<dim3(32, 16, 4), 256, 0, stream>>>(Vbuf, Vtbuf);
    attn_kernel<<<dim3(32, 16, 4), 256, 0, stream>>>(Qbuf, Kbuf, Vtbuf, Abuf);
    transpose_w<<<dim3(16, 16, 1), 256, 0, stream>>>(Wo, Wo, Wo, WtO);
    gemm_bt<1><<<dim3(64, 8, 1), 256, 0, stream>>>(Abuf, WtO, bo, bo, bo,
                                                   d_out, M_, D_, D_);
}